// Round 1
// baseline (1659.247 us; speedup 1.0000x reference)
//
#include <hip/hip_runtime.h>

// Problem constants (from reference setup_inputs)
#define KK   27
#define MM   80000
#define NN   200000
#define INC  64
#define OUTC 128
#define RIN  48
#define ROUT 96

#define BLOCKS_PER_K 80
#define ENTRIES_PER_BLOCK ((MM + BLOCKS_PER_K - 1) / BLOCKS_PER_K)  // 1000

__global__ __launch_bounds__(192)
void sparse_conv_scatter(const float* __restrict__ feat,
                         const float* __restrict__ w,
                         const int* __restrict__ imap,
                         const int* __restrict__ omap,
                         float* __restrict__ out)
{
    __shared__ float wlds[RIN * ROUT];  // 48*96*4 = 18432 B

    const int k = blockIdx.y;
    // stage w[k][:RIN][:ROUT] from (K, INC, OUTC) layout
    const float* wk = w + (size_t)k * INC * OUTC;
    for (int idx = threadIdx.x; idx < RIN * ROUT; idx += 192) {
        int i = idx / ROUT;
        int o = idx - i * ROUT;
        wlds[idx] = wk[i * OUTC + o];
    }
    __syncthreads();

    const int sub = threadIdx.x / 96;   // which of the 2 entries this thread works on
    const int oc  = threadIdx.x % 96;   // output channel

    const int m0 = blockIdx.x * ENTRIES_PER_BLOCK;
    const int m1 = min(m0 + ENTRIES_PER_BLOCK, MM);

    const int* imk = imap + (size_t)k * MM;
    const int* omk = omap + (size_t)k * MM;

    for (int m = m0 + sub; m < m1; m += 2) {
        const int fin  = imk[m];
        const int fout = omk[m];
        const float4* f4 = (const float4*)(feat + (size_t)fin * RIN);

        float acc = 0.f;
        #pragma unroll
        for (int i4 = 0; i4 < RIN / 4; ++i4) {
            float4 v = f4[i4];
            acc += v.x * wlds[(i4 * 4 + 0) * ROUT + oc];
            acc += v.y * wlds[(i4 * 4 + 1) * ROUT + oc];
            acc += v.z * wlds[(i4 * 4 + 2) * ROUT + oc];
            acc += v.w * wlds[(i4 * 4 + 3) * ROUT + oc];
        }
        atomicAdd(&out[(size_t)fout * ROUT + oc], acc);
    }
}

extern "C" void kernel_launch(void* const* d_in, const int* in_sizes, int n_in,
                              void* d_out, int out_size, void* d_ws, size_t ws_size,
                              hipStream_t stream)
{
    const float* features = (const float*)d_in[0];
    const float* kernel_w = (const float*)d_in[1];
    const int*   in_map   = (const int*)d_in[2];
    const int*   out_map  = (const int*)d_in[3];
    float*       out      = (float*)d_out;

    // zero the output accumulator (fp32 zeros == all-zero bytes)
    hipMemsetAsync(d_out, 0, (size_t)out_size * sizeof(float), stream);

    dim3 grid(BLOCKS_PER_K, KK);
    sparse_conv_scatter<<<grid, 192, 0, stream>>>(features, kernel_w, in_map, out_map, out);
}